// Round 18
// baseline (198.390 us; speedup 1.0000x reference)
//
#include <hip/hip_runtime.h>

// Problem constants
#define TT 4096      // tokens (B*L)
#define DD 1024      // model dim
#define HH 2048      // hidden dim
#define EE 8         // experts
#define TK 8192      // T*K pairs (K=2)

typedef short  bf16x8 __attribute__((ext_vector_type(8)));
typedef float  f32x4  __attribute__((ext_vector_type(4)));

__device__ __forceinline__ unsigned short f2b(float f) {
    unsigned int u = __float_as_uint(f);
    unsigned int r = (u + 0x7fffu + ((u >> 16) & 1u)) >> 16;  // RNE
    return (unsigned short)r;
}
__device__ __forceinline__ float b2f(unsigned short b) {
    return __uint_as_float(((unsigned int)b) << 16);
}

#define GLOAD_LDS16(SRC, DST) __builtin_amdgcn_global_load_lds( \
    (const __attribute__((address_space(1))) unsigned int*)(SRC), \
    (__attribute__((address_space(3))) unsigned int*)(DST), 16, 0, 0)

// ========= PREP2: gating (blocks 0..1023) + convw 128x128 bf16-tile (1024..3071) =========
__global__ __launch_bounds__(256) void prep2(
    const float* __restrict__ w1, const float* __restrict__ w2,
    unsigned short* __restrict__ w1bT, unsigned short* __restrict__ w2bT,
    const float* __restrict__ x, const float* __restrict__ wg, const float* __restrict__ eps,
    float* __restrict__ stats_f, int* __restrict__ stats_i,
    int* __restrict__ top_i, float* __restrict__ top_g,
    unsigned short* __restrict__ xb) {
    __shared__ unsigned short tile[128][130];
    int b = blockIdx.x;
    if (b >= 1024) {
        int cb = b - 1024;
        const float* src; unsigned short* dst; int Kd, Nd, lb;
        if (cb < 1024) { src = w1; dst = w1bT; Kd = 1024; Nd = 2048; lb = cb; }
        else           { src = w2; dst = w2bT; Kd = 2048; Nd = 1024; lb = cb - 1024; }
        int nx = Nd >> 7, ny = Kd >> 7;
        int bx = lb % nx, by = (lb / nx) % ny, e = lb / (nx * ny);
        int n0 = bx * 128, k0 = by * 128;
        const float* s = src + (size_t)e * Kd * Nd;
        unsigned short* d = dst + (size_t)e * Kd * Nd;
        int rg = threadIdx.x >> 5;            // 0..7
        int c4 = (threadIdx.x & 31) * 4;      // 0..124
#pragma unroll
        for (int i = 0; i < 16; i++) {
            int r = rg + i * 8;
            float4 v = *(const float4*)(s + (size_t)(k0 + r) * Nd + n0 + c4);
            ushort2 lo, hi;
            lo.x = f2b(v.x); lo.y = f2b(v.y);
            hi.x = f2b(v.z); hi.y = f2b(v.w);
            *(ushort2*)(&tile[r][c4])     = lo;
            *(ushort2*)(&tile[r][c4 + 2]) = hi;
        }
        __syncthreads();
#pragma unroll
        for (int i = 0; i < 16; i++) {
            int n = rg + i * 8;
            ushort4 o;
            o.x = tile[c4 + 0][n];
            o.y = tile[c4 + 1][n];
            o.z = tile[c4 + 2][n];
            o.w = tile[c4 + 3][n];
            *(ushort4*)(d + (size_t)(n0 + n) * Kd + k0 + c4) = o;
        }
    } else {
        __shared__ float l_psum[8], l_gsum[8], l_zl;
        __shared__ int   l_cr[8], l_cp[8];
        int tid = threadIdx.x;
        if (tid < 8) { l_psum[tid] = 0.f; l_gsum[tid] = 0.f; l_cr[tid] = 0; l_cp[tid] = 0; }
        if (tid == 0) l_zl = 0.f;
        __syncthreads();
        int wave = tid >> 6, lane = tid & 63;
        int t = b * 4 + wave;
        const float* xr = x + (size_t)t * DD;
        unsigned short* xbr = xb + (size_t)t * DD;
#pragma unroll
        for (int i = 0; i < 4; i++) {
            int idx = lane + i * 64;
            float4 v = ((const float4*)xr)[idx];
            ushort4 o;
            o.x = f2b(v.x); o.y = f2b(v.y); o.z = f2b(v.z); o.w = f2b(v.w);
            ((ushort4*)xbr)[idx] = o;
        }
        int sub = lane >> 2, part = lane & 3;
        float a0 = 0.f, a1 = 0.f, a2 = 0.f, a3 = 0.f;
#pragma unroll 8
        for (int i = 0; i < 64; i++) {
            int dd = sub + i * 16;
            float xv = xr[dd];
            float4 w4 = *(const float4*)(wg + dd * 16 + part * 4);
            a0 += xv * w4.x; a1 += xv * w4.y; a2 += xv * w4.z; a3 += xv * w4.w;
        }
#pragma unroll
        for (int o = 4; o < 64; o <<= 1) {
            a0 += __shfl_xor(a0, o, 64);
            a1 += __shfl_xor(a1, o, 64);
            a2 += __shfl_xor(a2, o, 64);
            a3 += __shfl_xor(a3, o, 64);
        }
        float f16v[16];
#pragma unroll
        for (int src2 = 0; src2 < 4; src2++) {
            f16v[src2 * 4 + 0] = __shfl(a0, src2, 64);
            f16v[src2 * 4 + 1] = __shfl(a1, src2, 64);
            f16v[src2 * 4 + 2] = __shfl(a2, src2, 64);
            f16v[src2 * 4 + 3] = __shfl(a3, src2, 64);
        }
        if (lane == 0) {
            float lg[8], p[8];
            float mx = -1e30f;
            for (int e2 = 0; e2 < 8; e2++) {
                float raw = f16v[8 + e2];
                float sp = (raw > 20.f) ? raw : log1pf(__expf(raw));
                float l = f16v[e2] + eps[(size_t)t * 8 + e2] * (sp + 0.01f);
                lg[e2] = l; mx = fmaxf(mx, l);
            }
            float se = 0.f;
            for (int e2 = 0; e2 < 8; e2++) { p[e2] = __expf(lg[e2] - mx); se += p[e2]; }
            float lse = mx + logf(se);
            float inv = 1.f / se;
            for (int e2 = 0; e2 < 8; e2++) p[e2] *= inv;
            int i0 = 0;
            for (int e2 = 1; e2 < 8; e2++) if (p[e2] > p[i0]) i0 = e2;
            int i1 = (i0 == 0) ? 1 : 0;
            for (int e2 = 0; e2 < 8; e2++) if (e2 != i0 && p[e2] > p[i1]) i1 = e2;
            float g0 = p[i0], g1 = p[i1];
            top_i[t * 2] = i0; top_i[t * 2 + 1] = i1;
            top_g[t * 2] = g0; top_g[t * 2 + 1] = g1;
            for (int e2 = 0; e2 < 8; e2++) atomicAdd(&l_psum[e2], p[e2]);
            atomicAdd(&l_gsum[i0], g0); atomicAdd(&l_gsum[i1], g1);
            atomicAdd(&l_zl, lse * lse);
            atomicAdd(&l_cr[i0], 1); atomicAdd(&l_cr[i1], 1);
            if (g0 > 0.f) atomicAdd(&l_cp[i0], 1);
            if (g1 > 0.f) atomicAdd(&l_cp[i1], 1);
        }
        __syncthreads();
        if (tid < 8) {
            atomicAdd(&stats_f[tid],      l_psum[tid]);
            atomicAdd(&stats_f[8 + tid],  l_gsum[tid]);
            atomicAdd(&stats_i[tid],      l_cr[tid]);
            atomicAdd(&stats_i[8 + tid],  l_cp[tid]);
        }
        if (tid == 0) atomicAdd(&stats_f[16], l_zl);
    }
}

// ---------------- scatter pairs + offsets + loss (fused) ----------------
__global__ void scatter(const int* __restrict__ top_i, int* __restrict__ stats_i,
                        const float* __restrict__ stats_f,
                        int* __restrict__ row_token, int* __restrict__ pair_pos,
                        float* __restrict__ loss_out) {
    __shared__ int lcnt[8], lbase[8], soffs[9];
    int tid = threadIdx.x;
    if (tid < 8) lcnt[tid] = 0;
    if (tid == 0) {
        int off = 0;
        for (int e = 0; e < 8; e++) { soffs[e] = off; off += stats_i[e]; }
        soffs[8] = off;
    }
    __syncthreads();
    int t = blockIdx.x * 256 + tid;
    int e0 = top_i[t * 2], e1 = top_i[t * 2 + 1];
    int p0 = atomicAdd(&lcnt[e0], 1);
    int p1 = atomicAdd(&lcnt[e1], 1);
    __syncthreads();
    if (tid < 8) lbase[tid] = atomicAdd(&stats_i[16 + tid], lcnt[tid]);
    __syncthreads();
    int idx0 = soffs[e0] + lbase[e0] + p0;
    int idx1 = soffs[e1] + lbase[e1] + p1;
    row_token[idx0] = t;
    row_token[idx1] = t;
    pair_pos[t * 2] = idx0;
    pair_pos[t * 2 + 1] = idx1;
    if (blockIdx.x == 0 && tid == 0) {
        for (int e = 0; e < 9; e++) stats_i[24 + e] = soffs[e];
        float gs = 0.f;
        for (int e = 0; e < 8; e++) gs += stats_f[8 + e];
        float var = 0.f;
        for (int e = 0; e < 8; e++) {
            float gn = stats_f[8 + e] / gs;
            float d = gn - 0.125f;
            var += d * d;
        }
        var /= 7.f;
        float cv = var / (0.015625f + 1e-10f);
        float ps = 0.f, cs = 0.f;
        for (int e = 0; e < 8; e++) { ps += stats_f[e]; cs += (float)stats_i[8 + e]; }
        float dot = 0.f;
        for (int e = 0; e < 8; e++) dot += (stats_f[e] / ps) * ((float)stats_i[8 + e] / cs);
        float sw = (1.f - dot) * 8.f;
        float zl = stats_f[16] / (float)TT;
        *loss_out = 0.01f * cv + 0.1f * sw + 0.0001f * zl;
    }
}

// ============ GEMM1: 256 mains (256x256, 8-phase, R5 ledger) + 256 tails (64x256 triple-buf) ====
template<int KTOT, int KSPLITS, int NTILES, bool GATHER, bool RELU>
__global__ __launch_bounds__(512, 1) void gemm_mt(
    const unsigned short* __restrict__ A,
    const unsigned short* __restrict__ Bt,
    unsigned short* __restrict__ C, long long split_stride,
    const int* __restrict__ row_token, const int* __restrict__ stats_i) {
    constexpr int KD   = KTOT / KSPLITS;
    constexpr int NK   = KD / 64;
    constexpr int NI   = NK / 2;
    constexpr int NDIM = NTILES * 256;
    static_assert(NTILES * KSPLITS == 8, "q must span 8");

    __shared__ __align__(16) unsigned short Al[2 * 256 * 64];
    __shared__ __align__(16) unsigned short Bl[2 * 256 * 64];

    const int* offs = stats_i + 24;
    int tid = threadIdx.x;
    int lane = tid & 63, wave = tid >> 6;

    if (blockIdx.x < 256) {
        int lin = blockIdx.x;
        int e   = lin & 7;
        int rem = lin >> 3;
        int q4  = rem & 7;
        int rt  = rem >> 3;
        int n0  = (q4 % NTILES) * 256;
        int split = q4 / NTILES;
        int off = offs[e];
        int ne  = offs[e + 1] - off;
        if (rt * 256 >= ne) return;

        int wm = wave >> 2, wn = wave & 3;

        const unsigned short* Asrc[4];
#pragma unroll
        for (int i = 0; i < 4; i++) {
            int glin = i * 512 + tid, row = glin >> 3, sl = glin & 7, g = sl ^ (row & 7);
            int arow;
            if (GATHER) arow = row_token[min(off + rt * 256 + row, TK - 1)];
            else        arow = min(off + rt * 256 + row, TK - 1);
            Asrc[i] = A + (size_t)arow * KTOT + split * KD + g * 8;
        }
        const unsigned short* Bte = Bt + (size_t)e * NDIM * KTOT;
        const unsigned short* Bsrc[4];
#pragma unroll
        for (int i = 0; i < 4; i++) {
            int glin = i * 512 + tid, row = glin >> 3, sl = glin & 7, g = sl ^ (row & 7);
            Bsrc[i] = Bte + (size_t)(n0 + row) * KTOT + split * KD + g * 8;
        }

        f32x4 acc[8][4];
#pragma unroll
        for (int m = 0; m < 8; m++)
#pragma unroll
            for (int n = 0; n < 4; n++)
#pragma unroll
                for (int i = 0; i < 4; i++) acc[m][n][i] = 0.f;

        bf16x8 bv[2][4], av[2][2];

#define STG_A(SLOT, KT, CC) GLOAD_LDS16(Asrc[CC] + (KT) * 64, Al + (SLOT) * 16384 + (CC) * 4096 + wave * 512)
#define STG_B(SLOT, KT, CC) GLOAD_LDS16(Bsrc[CC] + (KT) * 64, Bl + (SLOT) * 16384 + (CC) * 4096 + wave * 512)

#define LOAD_B(SLOT) do { \
    _Pragma("unroll") for (int kk2 = 0; kk2 < 2; kk2++) \
    _Pragma("unroll") for (int n = 0; n < 4; n++) { \
        int row = wn * 64 + n * 16 + (lane & 15); \
        int g = (kk2 * 4 + (lane >> 4)) ^ (row & 7); \
        bv[kk2][n] = *(const bf16x8*)(Bl + (SLOT) * 16384 + row * 64 + g * 8); \
    } } while (0)

#define LOAD_AQ(SLOT, QQ) do { \
    _Pragma("unroll") for (int kk2 = 0; kk2 < 2; kk2++) \
    _Pragma("unroll") for (int mi = 0; mi < 2; mi++) { \
        int row = wm * 128 + (QQ) * 32 + mi * 16 + (lane & 15); \
        int g = (kk2 * 4 + (lane >> 4)) ^ (row & 7); \
        av[kk2][mi] = *(const bf16x8*)(Al + (SLOT) * 16384 + row * 64 + g * 8); \
    } } while (0)

#define MFMA_Q(QQ) do { \
    _Pragma("unroll") for (int kk2 = 0; kk2 < 2; kk2++) \
    _Pragma("unroll") for (int mi = 0; mi < 2; mi++) \
    _Pragma("unroll") for (int n = 0; n < 4; n++) \
        acc[(QQ) * 2 + mi][n] = __builtin_amdgcn_mfma_f32_16x16x32_bf16(av[kk2][mi], bv[kk2][n], acc[(QQ) * 2 + mi][n], 0, 0, 0); \
    } while (0)

#define PHASE(SLOT, QQ, STAGE_STMT, WAIT_STMT) do { \
    if ((QQ) == 0) LOAD_B(SLOT); \
    LOAD_AQ(SLOT, QQ); \
    STAGE_STMT; \
    __builtin_amdgcn_s_barrier(); \
    asm volatile("s_waitcnt lgkmcnt(0)" ::: "memory"); \
    __builtin_amdgcn_s_setprio(1); \
    MFMA_Q(QQ); \
    __builtin_amdgcn_s_setprio(0); \
    WAIT_STMT; \
    __builtin_amdgcn_s_barrier(); \
    } while (0)

#pragma unroll
        for (int c = 0; c < 4; c++) STG_B(0, 0, c);
#pragma unroll
        for (int c = 0; c < 4; c++) STG_A(0, 0, c);
#pragma unroll
        for (int c = 0; c < 4; c++) STG_B(1, 1, c);
        STG_A(1, 1, 0); STG_A(1, 1, 2);
        asm volatile("s_waitcnt vmcnt(6)" ::: "memory");
        __builtin_amdgcn_s_barrier();

#pragma unroll 1
        for (int it = 0; it < NI; ++it) {
            int u = 2 * it, v = u + 1;
            bool ns = (it + 1 < NI);
            PHASE(0, 0, { STG_A(1, v, 1); STG_A(1, v, 3); }, {});
            PHASE(0, 1, { if (ns) { STG_B(0, u + 2, 0); STG_B(0, u + 2, 1); } }, {});
            PHASE(0, 2, { if (ns) { STG_B(0, u + 2, 2); STG_B(0, u + 2, 3); } }, {});
            PHASE(0, 3, { if (ns) { STG_A(0, u + 2, 0); STG_A(0, u + 2, 2); } },
                        { if (ns) asm volatile("s_waitcnt vmcnt(6)" ::: "memory");
                          else    asm volatile("s_waitcnt vmcnt(0)" ::: "memory"); });
            PHASE(1, 0, { if (ns) { STG_A(0, u + 2, 1); STG_A(0, u + 2, 3); } }, {});
            PHASE(1, 1, { if (ns) { STG_B(1, v + 2, 0); STG_B(1, v + 2, 1); } }, {});
            PHASE(1, 2, { if (ns) { STG_B(1, v + 2, 2); STG_B(1, v + 2, 3); } }, {});
            PHASE(1, 3, { if (ns) { STG_A(1, v + 2, 0); STG_A(1, v + 2, 2); } },
                        { if (ns) asm volatile("s_waitcnt vmcnt(6)" ::: "memory"); });
        }
#undef PHASE
#undef MFMA_Q
#undef LOAD_AQ
#undef LOAD_B
#undef STG_A
#undef STG_B

        unsigned short* Cb = C + (ptrdiff_t)split * split_stride;
#pragma unroll
        for (int m = 0; m < 8; m++) {
            int rr0 = rt * 256 + wm * 128 + m * 16 + (lane >> 4) * 4;
#pragma unroll
            for (int i = 0; i < 4; i++) {
                if (rr0 + i < ne) {
                    size_t grow = (size_t)(off + rr0 + i);
#pragma unroll
                    for (int n = 0; n < 4; n++) {
                        int col = n0 + wn * 64 + n * 16 + (lane & 15);
                        float vvv = acc[m][n][i];
                        if (RELU) vvv = fmaxf(vvv, 0.f);
                        Cb[grow * NDIM + col] = f2b(vvv);
                    }
                }
            }
        }
    } else {
        // TAIL: 64x256, triple-buffered counted-vmcnt (5 loads/stage, vmcnt(5))
        int t   = blockIdx.x - 256;
        int e   = t & 7;
        int rem = t >> 3;
        int q4  = rem & 7;
        int s0  = rem >> 3;
        int n0  = (q4 % NTILES) * 256;
        int split = q4 / NTILES;
        int off = offs[e];
        int ne  = offs[e + 1] - off;
        int m0  = 1024 + s0 * 64;
        if (m0 >= ne) return;

        int wm = wave >> 2, wn = wave & 3;

        const unsigned short* Asrc;
        {
            int row = tid >> 3, sl = tid & 7, g = sl ^ (row & 7);
            int arow;
            if (GATHER) arow = row_token[min(off + m0 + row, TK - 1)];
            else        arow = min(off + m0 + row, TK - 1);
            Asrc = A + (size_t)arow * KTOT + split * KD + g * 8;
        }
        const unsigned short* Bte = Bt + (size_t)e * NDIM * KTOT;
        const unsigned short* Bsrc[4];
#pragma unroll
        for (int i = 0; i < 4; i++) {
            int glin = i * 512 + tid, row = glin >> 3, sl = glin & 7, g = sl ^ (row & 7);
            Bsrc[i] = Bte + (size_t)(n0 + row) * KTOT + split * KD + g * 8;
        }

        f32x4 acc2[2][4];
#pragma unroll
        for (int m = 0; m < 2; m++)
#pragma unroll
            for (int n = 0; n < 4; n++)
#pragma unroll
                for (int i = 0; i < 4; i++) acc2[m][n][i] = 0.f;

#define TTSG(S, KT) do { \
    unsigned short* Ab_ = Al + (S) * 4096; \
    unsigned short* Bb_ = ((S) == 2) ? (Al + 16384) : (Bl + (S) * 16384); \
    GLOAD_LDS16(Asrc + (KT) * 64, Ab_ + wave * 512); \
    _Pragma("unroll") for (int c_ = 0; c_ < 4; c_++) \
        GLOAD_LDS16(Bsrc[c_] + (KT) * 64, Bb_ + c_ * 4096 + wave * 512); \
} while (0)

        TTSG(0, 0);
        TTSG(1, 1);
        int sb = 0;
#pragma unroll 1
        for (int kt = 0; kt < NK; ++kt) {
            if (kt + 1 < NK) asm volatile("s_waitcnt vmcnt(5)" ::: "memory");
            else             asm volatile("s_waitcnt vmcnt(0)" ::: "memory");
            __builtin_amdgcn_s_barrier();
            if (kt + 2 < NK) { int s2 = sb + 2; if (s2 >= 3) s2 -= 3; TTSG(s2, kt + 2); }
            const unsigned short* Ab = Al + sb * 4096;
            const unsigned short* Bb = (sb == 2) ? (Al + 16384) : (Bl + sb * 16384);
            bf16x8 a2[2][2], b2[2][4];
#pragma unroll
            for (int kk2 = 0; kk2 < 2; kk2++) {
#pragma unroll
                for (int mi = 0; mi < 2; mi++) {
                    int row = wm * 32 + mi * 16 + (lane & 15);
                    int g = (kk2 * 4 + (lane >> 4)) ^ (row & 7);
                    a2[kk2][mi] = *(const bf16x8*)(Ab + row * 64 + g * 8);
                }
#pragma unroll
                for (int n = 0; n < 4; n++) {
                    int row = wn * 64 + n * 16 + (lane & 15);
                    int g = (kk2 * 4 + (lane >> 4)) ^ (row & 7);
                    b2[kk2][n] = *(const bf16x8*)(Bb + row * 64 + g * 8);
                }
            }
#pragma unroll
            for (int kk2 = 0; kk2 < 2; kk2++)
#pragma unroll
                for (int mi = 0; mi < 2; mi++)
#pragma unroll
                    for (int n = 0; n < 4; n++)
                        acc2[mi][n] = __builtin_amdgcn_mfma_f32_16x16x32_bf16(a2[kk2][mi], b2[kk2][n], acc2[mi][n], 0, 0, 0);
            sb = (sb == 2) ? 0 : sb + 1;
        }
#undef TTSG

        unsigned short* Cb = C + (ptrdiff_t)split * split_stride;
#pragma unroll
        for (int mi = 0; mi < 2; mi++) {
            int rr0 = m0 + wm * 32 + mi * 16 + (lane >> 4) * 4;
#pragma unroll
            for (int i = 0; i < 4; i++) {
                if (rr0 + i < ne) {
                    size_t grow = (size_t)(off + rr0 + i);
#pragma unroll
                    for (int n = 0; n < 4; n++) {
                        int col = n0 + wn * 64 + n * 16 + (lane & 15);
                        float vvv = acc2[mi][n][i];
                        if (RELU) vvv = fmaxf(vvv, 0.f);
                        Cb[grow * NDIM + col] = f2b(vvv);
                    }
                }
            }
        }
    }
}

// ============ GEMM2F: 128x256 tile, FULL K=2048, no split-K. 8-phase ledger (R6 seg1, verified):
//   prologue: B(K0)x4, A(K0)x2 -> slot0; B(K1)x4 -> slot1; vmcnt(4); barrier.
//   ph0: A0(v)->s1 | ph1: A1(v)->s1, B01(u+2)->s0 | ph2: B23(u+2)->s0 | ph3: wait vm(4)
//   ph4: A01(u+2)->s0 | ph5: B01(v+2)->s1 | ph6: B23(v+2)->s1 | ph7: wait vm(4)
// Mains: 256 blocks (8e x 8m x 4n). Tails: rows 1024+s*64 (q4<4 active). LDS 96KB.
__global__ __launch_bounds__(512, 1) void gemm2f(
    const unsigned short* __restrict__ A,
    const unsigned short* __restrict__ Bt,
    unsigned short* __restrict__ C,
    const int* __restrict__ row_token, const int* __restrict__ stats_i) {
    constexpr int KTOT = 2048, NDIM = 1024;
    constexpr int NK = 32, NI = 16;

    __shared__ __align__(16) unsigned short Al[2 * 128 * 64];   // 32 KB (slot = 8192 shorts)
    __shared__ __align__(16) unsigned short Bl[2 * 256 * 64];   // 64 KB (slot = 16384 shorts)

    const int* offs = stats_i + 24;
    int tid = threadIdx.x;
    int lane = tid & 63, wave = tid >> 6;
    int wm = wave >> 2, wn = wave & 3;

    if (blockIdx.x < 256) {
        int lin = blockIdx.x;
        int e   = lin & 7;
        int rem = lin >> 3;          // 0..31
        int q4  = rem & 3;           // n-tile
        int rt  = rem >> 2;          // 0..7 m-tile (128 rows)
        int n0  = q4 * 256;
        int off = offs[e];
        int ne  = offs[e + 1] - off;
        if (rt * 128 >= ne) return;

        const unsigned short* Asrc[2];
#pragma unroll
        for (int i = 0; i < 2; i++) {
            int glin = i * 512 + tid, row = glin >> 3, sl = glin & 7, g = sl ^ (row & 7);
            int arow = min(off + rt * 128 + row, TK - 1);
            Asrc[i] = A + (size_t)arow * KTOT + g * 8;
        }
        const unsigned short* Bte = Bt + (size_t)e * NDIM * KTOT;
        const unsigned short* Bsrc[4];
#pragma unroll
        for (int i = 0; i < 4; i++) {
            int glin = i * 512 + tid, row = glin >> 3, sl = glin & 7, g = sl ^ (row & 7);
            Bsrc[i] = Bte + (size_t)(n0 + row) * KTOT + g * 8;
        }

        f32x4 acc[4][4];
#pragma unroll
        for (int m = 0; m < 4; m++)
#pragma unroll
            for (int n = 0; n < 4; n++)
#pragma unroll
                for (int i = 0; i < 4; i++) acc[m][n][i] = 0.f;

        bf16x8 bv[2][4], av[2];

#define S2A(SLOT, KT, CC) GLOAD_LDS16(Asrc[CC] + (KT) * 64, Al + (SLOT) * 8192 + (CC) * 4096 + wave * 512)
#define S2B(SLOT, KT, CC) GLOAD_LDS16(Bsrc[CC] + (KT) * 64, Bl + (SLOT) * 16384 + (CC) * 4096 + wave * 512)

#define LD2B(SLOT) do { \
    _Pragma("unroll") for (int kk2 = 0; kk2 < 2; kk2++) \
    _Pragma("unroll") for (int n = 0; n < 4; n++) { \
        int row = wn * 64 + n * 16 + (lane & 15); \
        int g = (kk2 * 4 + (lane >> 4)) ^ (row & 7); \
        bv[kk2][n] = *(const bf16x8*)(Bl + (SLOT) * 16384 + row * 64 + g * 8); \
    } } while (0)

#define LD2A(SLOT, QQ) do { \
    _Pragma("unroll") for (int kk2 = 0; kk2 < 2; kk2++) { \
        int row = wm * 64 + (QQ) * 16 + (lane & 15); \
        int g = (kk2 * 4 + (lane >> 4)) ^ (row & 7); \
        av[kk2] = *(const bf16x8*)(Al + (SLOT) * 8192 + row * 64 + g * 8); \
    } } while (0)

#define MM2(QQ) do { \
    _Pragma("unroll") for (int kk2 = 0; kk2 < 2; kk2++) \
    _Pragma("unroll") for (int n = 0; n < 4; n++) \
        acc[QQ][n] = __builtin_amdgcn_mfma_f32_16x16x32_bf16(av[kk2], bv[kk2][n], acc[QQ][n], 0, 0, 0); \
    } while (0)

#define PH2(SLOT, QQ, STAGE_STMT, WAIT_STMT) do { \
    if ((QQ) == 0) LD2B(SLOT); \
    LD2A(SLOT, QQ); \
    STAGE_STMT; \
    __builtin_amdgcn_s_barrier(); \
    asm volatile("s_waitcnt lgkmcnt(0)" ::: "memory"); \
    __builtin_amdgcn_s_setprio(1); \
    MM2(QQ); \
    __builtin_amdgcn_s_setprio(0); \
    WAIT_STMT; \
    __builtin_amdgcn_s_barrier(); \
    } while (0)

        // prologue
#pragma unroll
        for (int c = 0; c < 4; c++) S2B(0, 0, c);
        S2A(0, 0, 0); S2A(0, 0, 1);
#pragma unroll
        for (int c = 0; c < 4; c++) S2B(1, 1, c);
        asm volatile("s_waitcnt vmcnt(4)" ::: "memory");
        __builtin_amdgcn_s_barrier();

#pragma unroll 1
        for (int it = 0; it < NI; ++it) {
            int u = 2 * it, v = u + 1;
            bool ns = (it + 1 < NI);
            PH2(0, 0, { S2A(1, v, 0); }, {});
            PH2(0, 1, { S2A(1, v, 1); if (ns) { S2B(0, u + 2, 0); S2B(0, u + 2, 1); } }, {});
            PH2(0, 2, { if (ns) { S2B(0, u + 2, 2); S2B(0, u + 2, 3); } }, {});
            PH2(0, 3, {}, { if (ns) asm volatile("s_waitcnt vmcnt(4)" ::: "memory");
                            else    asm volatile("s_waitcnt vmcnt(0)" ::: "memory"); });
            PH2(1, 0, { if (ns) { S2A(0, u + 2, 0); S2A(0, u + 2, 1); } }, {});
            PH2(1, 1, { if (ns) { S2B(1, v + 2, 0); S2B(1, v + 2, 1); } }, {});
            PH2(1, 2, { if (ns) { S2B(1, v + 2, 2); S2B(1, v + 2, 3); } }, {});
            PH2(1, 3, {}, { if (ns) asm volatile("s_waitcnt vmcnt(4)" ::: "memory");
                            else    asm volatile("s_waitcnt vmcnt(0)" ::: "memory"); });
        }
#undef PH2
#undef MM2
#undef LD2A
#undef LD2B
#undef S2A
#undef S2B

#pragma unroll
        for (int m = 0; m < 4; m++) {
            int rr0 = rt * 128 + wm * 64 + m * 16 + (lane >> 4) * 4;
#pragma unroll
            for (int i = 0; i < 4; i++) {
                if (rr0 + i < ne) {
                    size_t grow = (size_t)(off + rr0 + i);
#pragma unroll
                    for (int n = 0; n < 4; n++) {
                        int col = n0 + wn * 64 + n * 16 + (lane & 15);
                        C[grow * NDIM + col] = f2b(acc[m][n][i]);
                    }
                }
            }
        }
    } else {
        // TAIL: 64x256, triple-buffered counted-vmcnt; only q4 < 4 active
        int t   = blockIdx.x - 256;
        int e   = t & 7;
        int rem = t >> 3;
        int q4  = rem & 7;
        int s0  = rem >> 3;
        if (q4 >= 4) return;
        int n0  = q4 * 256;
        int off = offs[e];
        int ne  = offs[e + 1] - off;
        int m0  = 1024 + s0 * 64;
        if (m0 >= ne) return;

        const unsigned short* Asrc;
        {
            int row = tid >> 3, sl = tid & 7, g = sl ^ (row & 7);
            int arow = min(off + m0 + row, TK - 1);
            Asrc = A + (size_t)arow * KTOT + g * 8;
        }
        const unsigned short* Bte = Bt + (size_t)e * NDIM * KTOT;
        const unsigned short* Bsrc[4];
#pragma unroll
        for (int i = 0; i < 4; i++) {
            int glin = i * 512 + tid, row = glin >> 3, sl = glin & 7, g = sl ^ (row & 7);
            Bsrc[i] = Bte + (size_t)(n0 + row) * KTOT + g * 8;
        }

        f32x4 acc2[2][4];
#pragma unroll
        for (int m = 0; m < 2; m++)
#pragma unroll
            for (int n = 0; n < 4; n++)
#pragma unroll
                for (int i = 0; i < 4; i++) acc2[m][n][i] = 0.f;

#define TTSG2(S, KT) do { \
    unsigned short* Ab_ = Al + (S) * 4096; \
    unsigned short* Bb_ = ((S) == 2) ? (Al + 12288) : (Bl + (S) * 16384); \
    GLOAD_LDS16(Asrc + (KT) * 64, Ab_ + wave * 512); \
    _Pragma("unroll") for (int c_ = 0; c_ < 4; c_++) \
        GLOAD_LDS16(Bsrc[c_] + (KT) * 64, Bb_ + c_ * 4096 + wave * 512); \
} while (0)
        // NOTE: stage-2 B buffer needs 16384 shorts but Al+12288 only has 4096 left in Al;
        // use Bl upper half alias instead: stage2 B lives at Bl + 8192 offset overlap is NOT safe.
        // -> simpler: stage 2's A at Al+8192? Al is only 2*8192. Use 2-stage double buffer here.
#undef TTSG2

#define TSTG(BUF, KT) do { \
    GLOAD_LDS16(Asrc + (KT) * 64, Al + (BUF) * 4096 + wave * 512); \
    _Pragma("unroll") for (int c_ = 0; c_ < 4; c_++) \
        GLOAD_LDS16(Bsrc[c_] + (KT) * 64, Bl + (BUF) * 16384 + c_ * 4096 + wave * 512); \
} while (0)

        TSTG(0, 0);
        asm volatile("s_waitcnt vmcnt(0)" ::: "memory");
        __builtin_amdgcn_s_barrier();

#pragma unroll 1
        for (int kt = 0; kt < NK; ++kt) {
            if (kt + 1 < NK) TSTG((kt & 1) ^ 1, kt + 1);
            int B = kt & 1;
            bf16x8 a2[2][2], b2[2][4];
#pragma unroll
            for (int kk2 = 0; kk2 < 2; kk2++) {
#pragma unroll
                for (int mi = 0; mi < 2; mi++) {
                    int row = wm * 32 + mi * 16 + (lane & 15);
                    int g = (kk2 * 4 + (lane >> 4)) ^ (row & 7);
                    a2[kk2][mi] = *(const bf16x8*)(Al + B * 4096 + row * 64 + g * 8);
                }
#pragma unroll
                for (int n = 0; n < 4; n++) {
                    int row = wn * 64 + n * 16 + (lane & 15);
                    int g = (kk2 * 4 + (lane >> 4)) ^ (row & 7);
                    b2[kk2][n] = *(const bf16x8*)(Bl + B * 16384 + row * 64 + g * 8);
                }
            }
#pragma unroll
            for (int kk2 = 0; kk2 < 2; kk2++)
#pragma unroll
                for (int mi = 0; mi < 2; mi++)
#pragma unroll
                    for (int n = 0; n < 4; n++)
                        acc2[mi][n] = __builtin_amdgcn_mfma_f32_16x16x32_bf16(a2[kk2][mi], b2[kk2][n], acc2[mi][n], 0, 0, 0);
            asm volatile("s_waitcnt vmcnt(0) lgkmcnt(0)" ::: "memory");
            __builtin_amdgcn_s_barrier();
        }
#undef TSTG

#pragma unroll
        for (int mi = 0; mi < 2; mi++) {
            int rr0 = m0 + wm * 32 + mi * 16 + (lane >> 4) * 4;
#pragma unroll
            for (int i = 0; i < 4; i++) {
                if (rr0 + i < ne) {
                    size_t grow = (size_t)(off + rr0 + i);
#pragma unroll
                    for (int n = 0; n < 4; n++) {
                        int col = n0 + wn * 64 + n * 16 + (lane & 15);
                        C[grow * NDIM + col] = f2b(acc2[mi][n][i]);
                    }
                }
            }
        }
    }
}

// ---------------- gated combine (single outp) ----------------
__global__ void combine(const unsigned short* __restrict__ outp,
                        const int* __restrict__ pair_pos, const float* __restrict__ top_g,
                        float* __restrict__ y) {
    int t = blockIdx.x;
    int tid = threadIdx.x;
    int i0 = pair_pos[t * 2], i1 = pair_pos[t * 2 + 1];
    float g0 = top_g[t * 2], g1 = top_g[t * 2 + 1];
    int d0 = tid * 4;
    ushort4 a = *(const ushort4*)(outp + (size_t)i0 * DD + d0);
    ushort4 b = *(const ushort4*)(outp + (size_t)i1 * DD + d0);
    float4 o;
    o.x = g0 * b2f(a.x) + g1 * b2f(b.x);
    o.y = g0 * b2f(a.y) + g1 * b2f(b.y);
    o.z = g0 * b2f(a.z) + g1 * b2f(b.z);
    o.w = g0 * b2f(a.w) + g1 * b2f(b.w);
    *(float4*)(y + (size_t)t * DD + d0) = o;
}

extern "C" void kernel_launch(void* const* d_in, const int* in_sizes, int n_in,
                              void* d_out, int out_size, void* d_ws, size_t ws_size,
                              hipStream_t stream) {
    const float* x   = (const float*)d_in[0];
    const float* wg  = (const float*)d_in[1];
    const float* w1  = (const float*)d_in[2];
    const float* w2  = (const float*)d_in[3];
    const float* eps = (const float*)d_in[4];
    float* y = (float*)d_out;
    char* ws = (char*)d_ws;

    unsigned short* xb    = (unsigned short*)(ws);                 //  8 MB
    unsigned short* w1bT  = (unsigned short*)(ws + 8388608);       // 32 MB  [E][H][D]
    unsigned short* w2bT  = (unsigned short*)(ws + 41943040);      // 32 MB  [E][D][H]
    unsigned short* hbuf  = (unsigned short*)(ws + 75497472);      // 32 MB  [TK][H]
    unsigned short* outp  = (unsigned short*)(ws + 109051904);     // 16 MB  [TK][D]
    int*   top_i    = (int*)(ws + 125829120);
    float* top_g    = (float*)(ws + 125861888);
    int*   row_token= (int*)(ws + 125894656);
    int*   pair_pos = (int*)(ws + 125927424);
    float* stats_f  = (float*)(ws + 125960192);
    int*   stats_i  = (int*)(ws + 125960192 + 128);

    hipMemsetAsync(ws + 125960192, 0, 768, stream);
    prep2<<<3072, 256, 0, stream>>>(w1, w2, w1bT, w2bT, x, wg, eps,
                                    stats_f, stats_i, top_i, top_g, xb);
    scatter<<<16, 256, 0, stream>>>(top_i, stats_i, stats_f, row_token, pair_pos, y + (size_t)TT * DD);
    // GEMM1: [pairs,1024] x [2048,1024]^T -> hbuf, relu, gathered A. 256 mains + 256 tails.
    gemm_mt<1024, 1, 8, true,  true ><<<512, 512, 0, stream>>>(
        xb, w1bT, hbuf, 0, row_token, stats_i);
    // GEMM2: [pairs,2048] x [1024,2048]^T -> outp, full-K (no splits). 256 mains + tails.
    gemm2f<<<512, 512, 0, stream>>>(hbuf, w2bT, outp, row_token, stats_i);
    combine<<<4096, 256, 0, stream>>>(outp, pair_pos, top_g, y);
}

// Round 19
// 181.382 us; speedup vs baseline: 1.0938x; 1.0938x over previous
//
#include <hip/hip_runtime.h>

// Problem constants
#define TT 4096      // tokens (B*L)
#define DD 1024      // model dim
#define HH 2048      // hidden dim
#define EE 8         // experts
#define TK 8192      // T*K pairs (K=2)

typedef short  bf16x8 __attribute__((ext_vector_type(8)));
typedef float  f32x4  __attribute__((ext_vector_type(4)));

__device__ __forceinline__ unsigned short f2b(float f) {
    unsigned int u = __float_as_uint(f);
    unsigned int r = (u + 0x7fffu + ((u >> 16) & 1u)) >> 16;  // RNE
    return (unsigned short)r;
}
__device__ __forceinline__ float b2f(unsigned short b) {
    return __uint_as_float(((unsigned int)b) << 16);
}

#define GLOAD_LDS16(SRC, DST) __builtin_amdgcn_global_load_lds( \
    (const __attribute__((address_space(1))) unsigned int*)(SRC), \
    (__attribute__((address_space(3))) unsigned int*)(DST), 16, 0, 0)

// ========= PREP2: gating (blocks 0..1023) + convw 128x128 bf16-tile (1024..3071) =========
// bf16 LDS tile (33.3KB) -> 4 blocks/CU. 512B-chunk reads / 256B-chunk writes (R14-verified).
__global__ __launch_bounds__(256) void prep2(
    const float* __restrict__ w1, const float* __restrict__ w2,
    unsigned short* __restrict__ w1bT, unsigned short* __restrict__ w2bT,
    const float* __restrict__ x, const float* __restrict__ wg, const float* __restrict__ eps,
    float* __restrict__ stats_f, int* __restrict__ stats_i,
    int* __restrict__ top_i, float* __restrict__ top_g,
    unsigned short* __restrict__ xb) {
    __shared__ unsigned short tile[128][130];
    int b = blockIdx.x;
    if (b >= 1024) {
        int cb = b - 1024;
        const float* src; unsigned short* dst; int Kd, Nd, lb;
        if (cb < 1024) { src = w1; dst = w1bT; Kd = 1024; Nd = 2048; lb = cb; }
        else           { src = w2; dst = w2bT; Kd = 2048; Nd = 1024; lb = cb - 1024; }
        int nx = Nd >> 7, ny = Kd >> 7;
        int bx = lb % nx, by = (lb / nx) % ny, e = lb / (nx * ny);
        int n0 = bx * 128, k0 = by * 128;
        const float* s = src + (size_t)e * Kd * Nd;
        unsigned short* d = dst + (size_t)e * Kd * Nd;
        int rg = threadIdx.x >> 5;            // 0..7
        int c4 = (threadIdx.x & 31) * 4;      // 0..124
#pragma unroll
        for (int i = 0; i < 16; i++) {
            int r = rg + i * 8;
            float4 v = *(const float4*)(s + (size_t)(k0 + r) * Nd + n0 + c4);
            ushort2 lo, hi;
            lo.x = f2b(v.x); lo.y = f2b(v.y);
            hi.x = f2b(v.z); hi.y = f2b(v.w);
            *(ushort2*)(&tile[r][c4])     = lo;
            *(ushort2*)(&tile[r][c4 + 2]) = hi;
        }
        __syncthreads();
#pragma unroll
        for (int i = 0; i < 16; i++) {
            int n = rg + i * 8;
            ushort4 o;
            o.x = tile[c4 + 0][n];
            o.y = tile[c4 + 1][n];
            o.z = tile[c4 + 2][n];
            o.w = tile[c4 + 3][n];
            *(ushort4*)(d + (size_t)(n0 + n) * Kd + k0 + c4) = o;
        }
    } else {
        __shared__ float l_psum[8], l_gsum[8], l_zl;
        __shared__ int   l_cr[8], l_cp[8];
        int tid = threadIdx.x;
        if (tid < 8) { l_psum[tid] = 0.f; l_gsum[tid] = 0.f; l_cr[tid] = 0; l_cp[tid] = 0; }
        if (tid == 0) l_zl = 0.f;
        __syncthreads();
        int wave = tid >> 6, lane = tid & 63;
        int t = b * 4 + wave;
        const float* xr = x + (size_t)t * DD;
        unsigned short* xbr = xb + (size_t)t * DD;
#pragma unroll
        for (int i = 0; i < 4; i++) {
            int idx = lane + i * 64;
            float4 v = ((const float4*)xr)[idx];
            ushort4 o;
            o.x = f2b(v.x); o.y = f2b(v.y); o.z = f2b(v.z); o.w = f2b(v.w);
            ((ushort4*)xbr)[idx] = o;
        }
        int sub = lane >> 2, part = lane & 3;
        float a0 = 0.f, a1 = 0.f, a2 = 0.f, a3 = 0.f;
#pragma unroll 8
        for (int i = 0; i < 64; i++) {
            int dd = sub + i * 16;
            float xv = xr[dd];
            float4 w4 = *(const float4*)(wg + dd * 16 + part * 4);
            a0 += xv * w4.x; a1 += xv * w4.y; a2 += xv * w4.z; a3 += xv * w4.w;
        }
#pragma unroll
        for (int o = 4; o < 64; o <<= 1) {
            a0 += __shfl_xor(a0, o, 64);
            a1 += __shfl_xor(a1, o, 64);
            a2 += __shfl_xor(a2, o, 64);
            a3 += __shfl_xor(a3, o, 64);
        }
        float f16v[16];
#pragma unroll
        for (int src2 = 0; src2 < 4; src2++) {
            f16v[src2 * 4 + 0] = __shfl(a0, src2, 64);
            f16v[src2 * 4 + 1] = __shfl(a1, src2, 64);
            f16v[src2 * 4 + 2] = __shfl(a2, src2, 64);
            f16v[src2 * 4 + 3] = __shfl(a3, src2, 64);
        }
        if (lane == 0) {
            float lg[8], p[8];
            float mx = -1e30f;
            for (int e2 = 0; e2 < 8; e2++) {
                float raw = f16v[8 + e2];
                float sp = (raw > 20.f) ? raw : log1pf(__expf(raw));
                float l = f16v[e2] + eps[(size_t)t * 8 + e2] * (sp + 0.01f);
                lg[e2] = l; mx = fmaxf(mx, l);
            }
            float se = 0.f;
            for (int e2 = 0; e2 < 8; e2++) { p[e2] = __expf(lg[e2] - mx); se += p[e2]; }
            float lse = mx + logf(se);
            float inv = 1.f / se;
            for (int e2 = 0; e2 < 8; e2++) p[e2] *= inv;
            int i0 = 0;
            for (int e2 = 1; e2 < 8; e2++) if (p[e2] > p[i0]) i0 = e2;
            int i1 = (i0 == 0) ? 1 : 0;
            for (int e2 = 0; e2 < 8; e2++) if (e2 != i0 && p[e2] > p[i1]) i1 = e2;
            float g0 = p[i0], g1 = p[i1];
            top_i[t * 2] = i0; top_i[t * 2 + 1] = i1;
            top_g[t * 2] = g0; top_g[t * 2 + 1] = g1;
            for (int e2 = 0; e2 < 8; e2++) atomicAdd(&l_psum[e2], p[e2]);
            atomicAdd(&l_gsum[i0], g0); atomicAdd(&l_gsum[i1], g1);
            atomicAdd(&l_zl, lse * lse);
            atomicAdd(&l_cr[i0], 1); atomicAdd(&l_cr[i1], 1);
            if (g0 > 0.f) atomicAdd(&l_cp[i0], 1);
            if (g1 > 0.f) atomicAdd(&l_cp[i1], 1);
        }
        __syncthreads();
        if (tid < 8) {
            atomicAdd(&stats_f[tid],      l_psum[tid]);
            atomicAdd(&stats_f[8 + tid],  l_gsum[tid]);
            atomicAdd(&stats_i[tid],      l_cr[tid]);
            atomicAdd(&stats_i[8 + tid],  l_cp[tid]);
        }
        if (tid == 0) atomicAdd(&stats_f[16], l_zl);
    }
}

// ---------------- scatter pairs + offsets + loss (fused) ----------------
__global__ void scatter(const int* __restrict__ top_i, int* __restrict__ stats_i,
                        const float* __restrict__ stats_f,
                        int* __restrict__ row_token, int* __restrict__ pair_pos,
                        float* __restrict__ loss_out) {
    __shared__ int lcnt[8], lbase[8], soffs[9];
    int tid = threadIdx.x;
    if (tid < 8) lcnt[tid] = 0;
    if (tid == 0) {
        int off = 0;
        for (int e = 0; e < 8; e++) { soffs[e] = off; off += stats_i[e]; }
        soffs[8] = off;
    }
    __syncthreads();
    int t = blockIdx.x * 256 + tid;
    int e0 = top_i[t * 2], e1 = top_i[t * 2 + 1];
    int p0 = atomicAdd(&lcnt[e0], 1);
    int p1 = atomicAdd(&lcnt[e1], 1);
    __syncthreads();
    if (tid < 8) lbase[tid] = atomicAdd(&stats_i[16 + tid], lcnt[tid]);
    __syncthreads();
    int idx0 = soffs[e0] + lbase[e0] + p0;
    int idx1 = soffs[e1] + lbase[e1] + p1;
    row_token[idx0] = t;
    row_token[idx1] = t;
    pair_pos[t * 2] = idx0;
    pair_pos[t * 2 + 1] = idx1;
    if (blockIdx.x == 0 && tid == 0) {
        for (int e = 0; e < 9; e++) stats_i[24 + e] = soffs[e];
        float gs = 0.f;
        for (int e = 0; e < 8; e++) gs += stats_f[8 + e];
        float var = 0.f;
        for (int e = 0; e < 8; e++) {
            float gn = stats_f[8 + e] / gs;
            float d = gn - 0.125f;
            var += d * d;
        }
        var /= 7.f;
        float cv = var / (0.015625f + 1e-10f);
        float ps = 0.f, cs = 0.f;
        for (int e = 0; e < 8; e++) { ps += stats_f[e]; cs += (float)stats_i[8 + e]; }
        float dot = 0.f;
        for (int e = 0; e < 8; e++) dot += (stats_f[e] / ps) * ((float)stats_i[8 + e] / cs);
        float sw = (1.f - dot) * 8.f;
        float zl = stats_f[16] / (float)TT;
        *loss_out = 0.01f * cv + 0.1f * sw + 0.0001f * zl;
    }
}

// ============ grouped GEMM: 256 main blocks (256x256, 8-phase, R5 ledger) + 256 tail blocks
// (64x256, TRIPLE-buffered counted-vmcnt: 5 loads/stage, vmcnt(5)) ============
template<int KTOT, int KSPLITS, int NTILES, bool GATHER, bool RELU>
__global__ __launch_bounds__(512, 1) void gemm_mt(
    const unsigned short* __restrict__ A,
    const unsigned short* __restrict__ Bt,
    unsigned short* __restrict__ C, long long split_stride,
    const int* __restrict__ row_token, const int* __restrict__ stats_i) {
    constexpr int KD   = KTOT / KSPLITS;   // K per block (1024)
    constexpr int NK   = KD / 64;          // 16
    constexpr int NI   = NK / 2;           // 8
    constexpr int NDIM = NTILES * 256;
    static_assert(NTILES * KSPLITS == 8, "q must span 8");

    __shared__ __align__(16) unsigned short Al[2 * 256 * 64];
    __shared__ __align__(16) unsigned short Bl[2 * 256 * 64];

    const int* offs = stats_i + 24;
    int tid = threadIdx.x;
    int lane = tid & 63, wave = tid >> 6;

    if (blockIdx.x < 256) {
        // ===================== MAIN: 256x256, 8-phase (R5 ledger, verbatim) =====================
        int lin = blockIdx.x;
        int e   = lin & 7;
        int rem = lin >> 3;
        int q4  = rem & 7;
        int rt  = rem >> 3;                // 0..3
        int n0  = (q4 % NTILES) * 256;
        int split = q4 / NTILES;
        int off = offs[e];
        int ne  = offs[e + 1] - off;
        if (rt * 256 >= ne) return;

        int wm = wave >> 2, wn = wave & 3;

        const unsigned short* Asrc[4];
#pragma unroll
        for (int i = 0; i < 4; i++) {
            int glin = i * 512 + tid, row = glin >> 3, sl = glin & 7, g = sl ^ (row & 7);
            int arow;
            if (GATHER) arow = row_token[min(off + rt * 256 + row, TK - 1)];
            else        arow = min(off + rt * 256 + row, TK - 1);
            Asrc[i] = A + (size_t)arow * KTOT + split * KD + g * 8;
        }
        const unsigned short* Bte = Bt + (size_t)e * NDIM * KTOT;
        const unsigned short* Bsrc[4];
#pragma unroll
        for (int i = 0; i < 4; i++) {
            int glin = i * 512 + tid, row = glin >> 3, sl = glin & 7, g = sl ^ (row & 7);
            Bsrc[i] = Bte + (size_t)(n0 + row) * KTOT + split * KD + g * 8;
        }

        f32x4 acc[8][4];
#pragma unroll
        for (int m = 0; m < 8; m++)
#pragma unroll
            for (int n = 0; n < 4; n++)
#pragma unroll
                for (int i = 0; i < 4; i++) acc[m][n][i] = 0.f;

        bf16x8 bv[2][4], av[2][2];

#define STG_A(SLOT, KT, CC) GLOAD_LDS16(Asrc[CC] + (KT) * 64, Al + (SLOT) * 16384 + (CC) * 4096 + wave * 512)
#define STG_B(SLOT, KT, CC) GLOAD_LDS16(Bsrc[CC] + (KT) * 64, Bl + (SLOT) * 16384 + (CC) * 4096 + wave * 512)

#define LOAD_B(SLOT) do { \
    _Pragma("unroll") for (int kk2 = 0; kk2 < 2; kk2++) \
    _Pragma("unroll") for (int n = 0; n < 4; n++) { \
        int row = wn * 64 + n * 16 + (lane & 15); \
        int g = (kk2 * 4 + (lane >> 4)) ^ (row & 7); \
        bv[kk2][n] = *(const bf16x8*)(Bl + (SLOT) * 16384 + row * 64 + g * 8); \
    } } while (0)

#define LOAD_AQ(SLOT, QQ) do { \
    _Pragma("unroll") for (int kk2 = 0; kk2 < 2; kk2++) \
    _Pragma("unroll") for (int mi = 0; mi < 2; mi++) { \
        int row = wm * 128 + (QQ) * 32 + mi * 16 + (lane & 15); \
        int g = (kk2 * 4 + (lane >> 4)) ^ (row & 7); \
        av[kk2][mi] = *(const bf16x8*)(Al + (SLOT) * 16384 + row * 64 + g * 8); \
    } } while (0)

#define MFMA_Q(QQ) do { \
    _Pragma("unroll") for (int kk2 = 0; kk2 < 2; kk2++) \
    _Pragma("unroll") for (int mi = 0; mi < 2; mi++) \
    _Pragma("unroll") for (int n = 0; n < 4; n++) \
        acc[(QQ) * 2 + mi][n] = __builtin_amdgcn_mfma_f32_16x16x32_bf16(av[kk2][mi], bv[kk2][n], acc[(QQ) * 2 + mi][n], 0, 0, 0); \
    } while (0)

#define PHASE(SLOT, QQ, STAGE_STMT, WAIT_STMT) do { \
    if ((QQ) == 0) LOAD_B(SLOT); \
    LOAD_AQ(SLOT, QQ); \
    STAGE_STMT; \
    __builtin_amdgcn_s_barrier(); \
    asm volatile("s_waitcnt lgkmcnt(0)" ::: "memory"); \
    __builtin_amdgcn_s_setprio(1); \
    MFMA_Q(QQ); \
    __builtin_amdgcn_s_setprio(0); \
    WAIT_STMT; \
    __builtin_amdgcn_s_barrier(); \
    } while (0)

        // prologue: K0 full -> slot0; K1 all but {A1,A3} -> slot1 (14 loads; wait oldest 8)
#pragma unroll
        for (int c = 0; c < 4; c++) STG_B(0, 0, c);
#pragma unroll
        for (int c = 0; c < 4; c++) STG_A(0, 0, c);
#pragma unroll
        for (int c = 0; c < 4; c++) STG_B(1, 1, c);
        STG_A(1, 1, 0); STG_A(1, 1, 2);
        asm volatile("s_waitcnt vmcnt(6)" ::: "memory");
        __builtin_amdgcn_s_barrier();

#pragma unroll 1
        for (int it = 0; it < NI; ++it) {
            int u = 2 * it, v = u + 1;
            bool ns = (it + 1 < NI);
            PHASE(0, 0, { STG_A(1, v, 1); STG_A(1, v, 3); }, {});
            PHASE(0, 1, { if (ns) { STG_B(0, u + 2, 0); STG_B(0, u + 2, 1); } }, {});
            PHASE(0, 2, { if (ns) { STG_B(0, u + 2, 2); STG_B(0, u + 2, 3); } }, {});
            PHASE(0, 3, { if (ns) { STG_A(0, u + 2, 0); STG_A(0, u + 2, 2); } },
                        { if (ns) asm volatile("s_waitcnt vmcnt(6)" ::: "memory");
                          else    asm volatile("s_waitcnt vmcnt(0)" ::: "memory"); });
            PHASE(1, 0, { if (ns) { STG_A(0, u + 2, 1); STG_A(0, u + 2, 3); } }, {});
            PHASE(1, 1, { if (ns) { STG_B(1, v + 2, 0); STG_B(1, v + 2, 1); } }, {});
            PHASE(1, 2, { if (ns) { STG_B(1, v + 2, 2); STG_B(1, v + 2, 3); } }, {});
            PHASE(1, 3, { if (ns) { STG_A(1, v + 2, 0); STG_A(1, v + 2, 2); } },
                        { if (ns) asm volatile("s_waitcnt vmcnt(6)" ::: "memory"); });
        }
#undef PHASE
#undef MFMA_Q
#undef LOAD_AQ
#undef LOAD_B
#undef STG_A
#undef STG_B

        unsigned short* Cb = C + (ptrdiff_t)split * split_stride;
#pragma unroll
        for (int m = 0; m < 8; m++) {
            int rr0 = rt * 256 + wm * 128 + m * 16 + (lane >> 4) * 4;
#pragma unroll
            for (int i = 0; i < 4; i++) {
                if (rr0 + i < ne) {
                    size_t grow = (size_t)(off + rr0 + i);
#pragma unroll
                    for (int n = 0; n < 4; n++) {
                        int col = n0 + wn * 64 + n * 16 + (lane & 15);
                        float vvv = acc[m][n][i];
                        if (RELU) vvv = fmaxf(vvv, 0.f);
                        Cb[grow * NDIM + col] = f2b(vvv);
                    }
                }
            }
        }
    } else {
        // ========== TAIL: 64x256, triple-buffered counted-vmcnt (5 loads/stage, vmcnt(5)) ==========
        int t   = blockIdx.x - 256;
        int e   = t & 7;
        int rem = t >> 3;
        int q4  = rem & 7;
        int s0  = rem >> 3;                // 0..3
        int n0  = (q4 % NTILES) * 256;
        int split = q4 / NTILES;
        int off = offs[e];
        int ne  = offs[e + 1] - off;
        int m0  = 1024 + s0 * 64;
        if (m0 >= ne) return;

        int wm = wave >> 2, wn = wave & 3;

        const unsigned short* Asrc;
        {
            int row = tid >> 3, sl = tid & 7, g = sl ^ (row & 7);
            int arow;
            if (GATHER) arow = row_token[min(off + m0 + row, TK - 1)];
            else        arow = min(off + m0 + row, TK - 1);
            Asrc = A + (size_t)arow * KTOT + split * KD + g * 8;
        }
        const unsigned short* Bte = Bt + (size_t)e * NDIM * KTOT;
        const unsigned short* Bsrc[4];
#pragma unroll
        for (int i = 0; i < 4; i++) {
            int glin = i * 512 + tid, row = glin >> 3, sl = glin & 7, g = sl ^ (row & 7);
            Bsrc[i] = Bte + (size_t)(n0 + row) * KTOT + split * KD + g * 8;
        }

        f32x4 acc2[2][4];
#pragma unroll
        for (int m = 0; m < 2; m++)
#pragma unroll
            for (int n = 0; n < 4; n++)
#pragma unroll
                for (int i = 0; i < 4; i++) acc2[m][n][i] = 0.f;

#define TTSG(S, KT) do { \
    unsigned short* Ab_ = Al + (S) * 4096; \
    unsigned short* Bb_ = ((S) == 2) ? (Al + 16384) : (Bl + (S) * 16384); \
    GLOAD_LDS16(Asrc + (KT) * 64, Ab_ + wave * 512); \
    _Pragma("unroll") for (int c_ = 0; c_ < 4; c_++) \
        GLOAD_LDS16(Bsrc[c_] + (KT) * 64, Bb_ + c_ * 4096 + wave * 512); \
} while (0)

        TTSG(0, 0);
        TTSG(1, 1);
        int sb = 0;
#pragma unroll 1
        for (int kt = 0; kt < NK; ++kt) {
            if (kt + 1 < NK) asm volatile("s_waitcnt vmcnt(5)" ::: "memory");
            else             asm volatile("s_waitcnt vmcnt(0)" ::: "memory");
            __builtin_amdgcn_s_barrier();
            if (kt + 2 < NK) { int s2 = sb + 2; if (s2 >= 3) s2 -= 3; TTSG(s2, kt + 2); }
            const unsigned short* Ab = Al + sb * 4096;
            const unsigned short* Bb = (sb == 2) ? (Al + 16384) : (Bl + sb * 16384);
            bf16x8 a2[2][2], b2[2][4];
#pragma unroll
            for (int kk2 = 0; kk2 < 2; kk2++) {
#pragma unroll
                for (int mi = 0; mi < 2; mi++) {
                    int row = wm * 32 + mi * 16 + (lane & 15);
                    int g = (kk2 * 4 + (lane >> 4)) ^ (row & 7);
                    a2[kk2][mi] = *(const bf16x8*)(Ab + row * 64 + g * 8);
                }
#pragma unroll
                for (int n = 0; n < 4; n++) {
                    int row = wn * 64 + n * 16 + (lane & 15);
                    int g = (kk2 * 4 + (lane >> 4)) ^ (row & 7);
                    b2[kk2][n] = *(const bf16x8*)(Bb + row * 64 + g * 8);
                }
            }
#pragma unroll
            for (int kk2 = 0; kk2 < 2; kk2++)
#pragma unroll
                for (int mi = 0; mi < 2; mi++)
#pragma unroll
                    for (int n = 0; n < 4; n++)
                        acc2[mi][n] = __builtin_amdgcn_mfma_f32_16x16x32_bf16(a2[kk2][mi], b2[kk2][n], acc2[mi][n], 0, 0, 0);
            sb = (sb == 2) ? 0 : sb + 1;
        }
#undef TTSG

        unsigned short* Cb = C + (ptrdiff_t)split * split_stride;
#pragma unroll
        for (int mi = 0; mi < 2; mi++) {
            int rr0 = m0 + wm * 32 + mi * 16 + (lane >> 4) * 4;
#pragma unroll
            for (int i = 0; i < 4; i++) {
                if (rr0 + i < ne) {
                    size_t grow = (size_t)(off + rr0 + i);
#pragma unroll
                    for (int n = 0; n < 4; n++) {
                        int col = n0 + wn * 64 + n * 16 + (lane & 15);
                        float vvv = acc2[mi][n][i];
                        if (RELU) vvv = fmaxf(vvv, 0.f);
                        Cb[grow * NDIM + col] = f2b(vvv);
                    }
                }
            }
        }
    }
}

// ---------------- gated combine (sums the two GEMM2 K-splits) ----------------
__global__ void combine(const unsigned short* __restrict__ o0,
                        const unsigned short* __restrict__ o1,
                        const int* __restrict__ pair_pos, const float* __restrict__ top_g,
                        float* __restrict__ y) {
    int t = blockIdx.x;
    int tid = threadIdx.x;
    int i0 = pair_pos[t * 2], i1 = pair_pos[t * 2 + 1];
    float g0 = top_g[t * 2], g1 = top_g[t * 2 + 1];
    int d0 = tid * 4;
    ushort4 a0 = *(const ushort4*)(o0 + (size_t)i0 * DD + d0);
    ushort4 a1 = *(const ushort4*)(o1 + (size_t)i0 * DD + d0);
    ushort4 b0 = *(const ushort4*)(o0 + (size_t)i1 * DD + d0);
    ushort4 b1 = *(const ushort4*)(o1 + (size_t)i1 * DD + d0);
    float4 o;
    o.x = g0 * (b2f(a0.x) + b2f(a1.x)) + g1 * (b2f(b0.x) + b2f(b1.x));
    o.y = g0 * (b2f(a0.y) + b2f(a1.y)) + g1 * (b2f(b0.y) + b2f(b1.y));
    o.z = g0 * (b2f(a0.z) + b2f(a1.z)) + g1 * (b2f(b0.z) + b2f(b1.z));
    o.w = g0 * (b2f(a0.w) + b2f(a1.w)) + g1 * (b2f(b0.w) + b2f(b1.w));
    *(float4*)(y + (size_t)t * DD + d0) = o;
}

extern "C" void kernel_launch(void* const* d_in, const int* in_sizes, int n_in,
                              void* d_out, int out_size, void* d_ws, size_t ws_size,
                              hipStream_t stream) {
    const float* x   = (const float*)d_in[0];
    const float* wg  = (const float*)d_in[1];
    const float* w1  = (const float*)d_in[2];
    const float* w2  = (const float*)d_in[3];
    const float* eps = (const float*)d_in[4];
    float* y = (float*)d_out;
    char* ws = (char*)d_ws;

    unsigned short* xb    = (unsigned short*)(ws);                 //  8 MB
    unsigned short* w1bT  = (unsigned short*)(ws + 8388608);       // 32 MB  [E][H][D]
    unsigned short* w2bT  = (unsigned short*)(ws + 41943040);      // 32 MB  [E][D][H]
    unsigned short* hbuf  = (unsigned short*)(ws + 75497472);      // 32 MB  [TK][H]
    unsigned short* outp0 = (unsigned short*)(ws + 109051904);     // 16 MB  [TK][D] split 0
    unsigned short* outp1 = (unsigned short*)(ws + 8388608);       // 16 MB  split 1 (reuses w1bT, dead after GEMM1)
    int*   top_i    = (int*)(ws + 125829120);
    float* top_g    = (float*)(ws + 125861888);
    int*   row_token= (int*)(ws + 125894656);
    int*   pair_pos = (int*)(ws + 125927424);
    float* stats_f  = (float*)(ws + 125960192);
    int*   stats_i  = (int*)(ws + 125960192 + 128);

    hipMemsetAsync(ws + 125960192, 0, 768, stream);
    prep2<<<3072, 256, 0, stream>>>(w1, w2, w1bT, w2bT, x, wg, eps,
                                    stats_f, stats_i, top_i, top_g, xb);
    scatter<<<16, 256, 0, stream>>>(top_i, stats_i, stats_f, row_token, pair_pos, y + (size_t)TT * DD);
    // GEMM1: [pairs,1024] x [2048,1024]^T -> hbuf, relu, gathered A. 256 mains + 256 tails.
    gemm_mt<1024, 1, 8, true,  true ><<<512, 512, 0, stream>>>(
        xb, w1bT, hbuf, 0, row_token, stats_i);
    // GEMM2: [pairs,2048] x [1024,2048]^T -> outp0/outp1 (split-K=2). 256 mains + 256 tails.
    gemm_mt<2048, 2, 4, false, false><<<512, 512, 0, stream>>>(
        hbuf, w2bT, outp0, (long long)(outp1 - outp0), row_token, stats_i);
    combine<<<4096, 256, 0, stream>>>(outp0, outp1, pair_pos, top_g, y);
}